// Round 10
// baseline (97.677 us; speedup 1.0000x reference)
//
#include <hip/hip_runtime.h>
#include <math.h>

#define BATCH 512
#define DIN   5120
#define DST   16
#define RK    160
#define NJ    192     // 160 dt_rank + 16 B + 16 C

typedef __attribute__((ext_vector_type(8))) __bf16 bf16x8;
typedef __attribute__((ext_vector_type(4))) float f32x4;
typedef __attribute__((ext_vector_type(8))) unsigned short ushort8;

// ws byte offsets (all 16B aligned)
#define OFF_XP    0u          // xP   [640 k8][512 b][8]  bf16
#define OFF_WP    5242880u    // WP   [640 k8][192 j][8]  bf16
#define OFF_WDTP  7208960u    // WdtP [20 k8][5120 d][8]  bf16
#define OFF_DTRP  15138816u   // dtrP [20 k8][512 b][8]   bf16
#define OFF_B     15302656u   // Bc   [512][16] f32
#define OFF_C     15335424u   // Cc   [512][16] f32

__device__ __forceinline__ unsigned short f2bf(float f) {
  unsigned int u = __float_as_uint(f);
  u = (u + 0x7FFFu + ((u >> 16) & 1u)) >> 16;   // RNE
  return (unsigned short)u;
}

// ---------------------------------------------------------------------------
// k_prep: pack bf16 operands (xP, WP, WdtP). 2160 blocks.
// ---------------------------------------------------------------------------
#define N1 (512*640)
#define N2 (192*640)
__global__ __launch_bounds__(256) void k_prep(
    const float* __restrict__ x, const float* __restrict__ Wdtr,
    const float* __restrict__ WB, const float* __restrict__ WC,
    const float* __restrict__ Wdt, char* __restrict__ ws)
{
  const int tid = blockIdx.x * 256 + threadIdx.x;
  const float* src; unsigned long long dst_idx;
  if (tid < N1) {
    const int b = tid / 640, k8 = tid - b * 640;
    src = x + (size_t)b * DIN + k8 * 8;
    dst_idx = (OFF_XP >> 4) + (size_t)k8 * 512 + b;
  } else if (tid < N1 + N2) {
    const int i = tid - N1;
    const int j = i / 640, k8 = i - j * 640;
    const float* row;
    if (j < RK)            row = Wdtr + (size_t)j * DIN;
    else if (j < RK + DST) row = WB   + (size_t)(j - RK) * DIN;
    else                   row = WC   + (size_t)(j - RK - DST) * DIN;
    src = row + k8 * 8;
    dst_idx = (OFF_WP >> 4) + (size_t)k8 * 192 + j;
  } else {
    const int i = tid - N1 - N2;          // < 5120*20
    const int d = i / 20, k8 = i - d * 20;
    src = Wdt + (size_t)d * RK + k8 * 8;
    dst_idx = (OFF_WDTP >> 4) + (size_t)k8 * 5120 + d;
  }
  const float4 f0 = *(const float4*)(src);
  const float4 f1 = *(const float4*)(src + 4);
  ushort8 o;
  o[0]=f2bf(f0.x); o[1]=f2bf(f0.y); o[2]=f2bf(f0.z); o[3]=f2bf(f0.w);
  o[4]=f2bf(f1.x); o[5]=f2bf(f1.y); o[6]=f2bf(f1.z); o[7]=f2bf(f1.w);
  ((ushort8*)ws)[dst_idx] = o;
}

// ---------------------------------------------------------------------------
// k_g1d: DIRECT GEMM1 (no split-K, no reduce). P[j,b] = sum_k W[j,k] x[b,k].
// One wave per 16x16 tile, 384 tiles = 384 blocks x 64 thr. K=5120 = 160
// MFMA steps, split over 4 independent accumulator chains (interleaved k8)
// to pipeline MFMA latency. Epilogue writes dtrP (bf16 packed) / Bc / Cc.
// ---------------------------------------------------------------------------
__global__ __launch_bounds__(64) void k_g1d(char* __restrict__ ws)
{
  const int wid = blockIdx.x;           // 0..383
  const int l   = threadIdx.x;          // 0..63
  const int jt  = wid >> 5, bt = wid & 31;
  const int j0  = jt * 16, b0 = bt * 16;

  const bf16x8* WPv = (const bf16x8*)(ws + OFF_WP);
  const bf16x8* xPv = (const bf16x8*)(ws + OFF_XP);

  const int lg = l >> 4, lr = l & 15;
  f32x4 a0 = {0.f,0.f,0.f,0.f}, a1 = a0, a2 = a0, a3 = a0;

  // k8 for chain c at step s: s*16 + c*4 + lg   (s<40, covers 640 k8)
  for (int s = 0; s < 40; ++s) {
    const int base = s * 16 + lg;
    a0 = __builtin_amdgcn_mfma_f32_16x16x32_bf16(
        WPv[(size_t)(base +  0) * 192 + j0 + lr],
        xPv[(size_t)(base +  0) * 512 + b0 + lr], a0, 0, 0, 0);
    a1 = __builtin_amdgcn_mfma_f32_16x16x32_bf16(
        WPv[(size_t)(base +  4) * 192 + j0 + lr],
        xPv[(size_t)(base +  4) * 512 + b0 + lr], a1, 0, 0, 0);
    a2 = __builtin_amdgcn_mfma_f32_16x16x32_bf16(
        WPv[(size_t)(base +  8) * 192 + j0 + lr],
        xPv[(size_t)(base +  8) * 512 + b0 + lr], a2, 0, 0, 0);
    a3 = __builtin_amdgcn_mfma_f32_16x16x32_bf16(
        WPv[(size_t)(base + 12) * 192 + j0 + lr],
        xPv[(size_t)(base + 12) * 512 + b0 + lr], a3, 0, 0, 0);
  }
  const f32x4 acc = (a0 + a1) + (a2 + a3);

  // epilogue: row = j0 + lg*4 + r, col = b0 + lr  (same mapping as before)
  const int b = b0 + lr;
  if (jt < 10) {                       // j < 160 -> dtrP bf16 [k8][b][8]
    unsigned short* dtrP = (unsigned short*)(ws + OFF_DTRP);
#pragma unroll
    for (int r = 0; r < 4; ++r) {
      const int j = j0 + lg * 4 + r;
      dtrP[((size_t)(j >> 3) * 512 + b) * 8 + (j & 7)] = f2bf(acc[r]);
    }
  } else if (jt == 10) {               // W_B rows
    float* Bc = (float*)(ws + OFF_B);
#pragma unroll
    for (int r = 0; r < 4; ++r)
      Bc[(size_t)b * DST + lg * 4 + r] = acc[r];
  } else {                             // W_C rows
    float* Cc = (float*)(ws + OFF_C);
#pragma unroll
    for (int r = 0; r < 4; ++r)
      Cc[(size_t)b * DST + lg * 4 + r] = acc[r];
  }
}

// ---------------------------------------------------------------------------
// k_g2y: FUSED dt-GEMM + softplus + state update + y (unchanged from R9).
// ---------------------------------------------------------------------------
__global__ __launch_bounds__(256) void k_g2y(
    const float* __restrict__ bdt, const float* __restrict__ A,
    const float* __restrict__ Dp,  const float* __restrict__ x,
    const float* __restrict__ h,   float* __restrict__ y,
    char* __restrict__ ws)
{
  __shared__ float sDT[4][16][17];
  __shared__ float sB[4][16][16];
  __shared__ float sC[4][16][16];
  __shared__ float sX[4][16][16];

  const int w = threadIdx.x >> 6;
  const int l = threadIdx.x & 63;
  const int wid = blockIdx.x * 4 + w;
  const int dtile = wid % 320, btile = wid / 320;
  const int d0 = dtile * 16, b0 = btile * 16;

  const bf16x8* dtrPv = (const bf16x8*)(ws + OFF_DTRP);
  const bf16x8* WdtPv = (const bf16x8*)(ws + OFF_WDTP);
  const float*  Bc    = (const float*)(ws + OFF_B);
  const float*  Cc    = (const float*)(ws + OFF_C);

  *(float4*)&((float*)sB[w])[l * 4] = *(const float4*)&Bc[b0 * DST + l * 4];
  *(float4*)&((float*)sC[w])[l * 4] = *(const float4*)&Cc[b0 * DST + l * 4];
  {
    const int xr = l >> 2, xc = (l & 3) * 4;
    *(float4*)&sX[w][xr][xc] = *(const float4*)&x[(size_t)(b0 + xr) * DIN + d0 + xc];
  }

  const int lg = l >> 4, lr = l & 15;
  f32x4 acc = {0.f, 0.f, 0.f, 0.f};
#pragma unroll
  for (int s = 0; s < 5; ++s) {
    const int k8 = s * 4 + lg;
    const bf16x8 av = dtrPv[(size_t)k8 * 512 + b0 + lr];
    const bf16x8 bv = WdtPv[(size_t)k8 * 5120 + d0 + lr];
    acc = __builtin_amdgcn_mfma_f32_16x16x32_bf16(av, bv, acc, 0, 0, 0);
  }
  const float bias = bdt[d0 + lr];
#pragma unroll
  for (int r = 0; r < 4; ++r) {
    const float pre = acc[r] + bias;
    sDT[w][lg * 4 + r][lr] = (pre > 20.f) ? pre : log1pf(__expf(pre));
  }
  __syncthreads();

  const int q = l & 3;
  const int Q = l >> 2;
  const int d = d0 + Q;
  const float4 A4 = *(const float4*)(A + (size_t)d * DST + q * 4);
  const float  Dv = Dp[d];

  const float* hp = h + ((size_t)b0 * DIN + d) * DST + q * 4;
  float* yp = y + (size_t)b0 * DIN + d;

  float4 hbuf[4];
#pragma unroll
  for (int j = 0; j < 4; ++j)
    hbuf[j] = *(const float4*)(hp + (size_t)j * (DIN * DST));

#pragma unroll
  for (int j = 0; j < 16; ++j) {
    const float4 h4 = hbuf[j & 3];
    if (j + 4 < 16)
      hbuf[j & 3] = *(const float4*)(hp + (size_t)(j + 4) * (DIN * DST));

    const float dtv = sDT[w][j][Q];
    const float xv  = sX[w][j][Q];
    const float dtx = dtv * xv;
    const float4 B4 = *(const float4*)&sB[w][j][q * 4];
    const float4 C4 = *(const float4*)&sC[w][j][q * 4];

    const float dA0 = __expf(A4.x * dtv);
    const float dA1 = __expf(A4.y * dtv);
    const float dA2 = __expf(A4.z * dtv);
    const float dA3 = __expf(A4.w * dtv);
    const float hn0 = fmaf(dA0, h4.x, dtx * B4.x);
    const float hn1 = fmaf(dA1, h4.y, dtx * B4.y);
    const float hn2 = fmaf(dA2, h4.z, dtx * B4.z);
    const float hn3 = fmaf(dA3, h4.w, dtx * B4.w);
    float p = hn0 * C4.x + hn1 * C4.y + hn2 * C4.z + hn3 * C4.w;

    p += __shfl_xor(p, 1);
    p += __shfl_xor(p, 2);
    if (q == 0) yp[(size_t)j * DIN] = fmaf(Dv, xv, p);
  }
}

extern "C" void kernel_launch(void* const* d_in, const int* in_sizes, int n_in,
                              void* d_out, int out_size, void* d_ws, size_t ws_size,
                              hipStream_t stream) {
  const float* x    = (const float*)d_in[0];
  const float* Wdtr = (const float*)d_in[1];
  const float* Wdt  = (const float*)d_in[2];
  const float* bdt  = (const float*)d_in[3];
  const float* WB   = (const float*)d_in[4];
  const float* WC   = (const float*)d_in[5];
  const float* A    = (const float*)d_in[6];
  const float* Dp   = (const float*)d_in[7];
  const float* h    = (const float*)d_in[8];
  float* y = (float*)d_out;
  char* ws = (char*)d_ws;

  k_prep<<<dim3(2160), 256, 0, stream>>>(x, Wdtr, WB, WC, Wdt, ws);
  k_g1d<<<dim3(384), 64, 0, stream>>>(ws);
  k_g2y<<<dim3(2560), 256, 0, stream>>>(bdt, A, Dp, x, h, y, ws);
}

// Round 11
// 73.569 us; speedup vs baseline: 1.3277x; 1.3277x over previous
//
#include <hip/hip_runtime.h>
#include <math.h>

#define BATCH 512
#define DIN   5120
#define DST   16
#define RK    160

typedef __attribute__((ext_vector_type(8))) __bf16 bf16x8;
typedef __attribute__((ext_vector_type(4))) float f32x4;

// ws byte offsets
#define OFF_DTRP  0u        // dtrP [20 k8][512 b][8]  bf16  (163840 B)
#define OFF_B     163840u   // Bc   [512][16] f32
#define OFF_C     196608u   // Cc   [512][16] f32

__device__ __forceinline__ unsigned short f2bf(float f) {
  unsigned int u = __float_as_uint(f);
  u = (u + 0x7FFFu + ((u >> 16) & 1u)) >> 16;   // RNE
  return (unsigned short)u;
}

__device__ __forceinline__ bf16x8 cvt8(const float4 a, const float4 b) {
  bf16x8 r;
  r[0] = (__bf16)a.x; r[1] = (__bf16)a.y; r[2] = (__bf16)a.z; r[3] = (__bf16)a.w;
  r[4] = (__bf16)b.x; r[5] = (__bf16)b.y; r[6] = (__bf16)b.z; r[7] = (__bf16)b.w;
  return r;
}

// ---------------------------------------------------------------------------
// k_g1f: GEMM1, split-K INSIDE the block. P[j,b] = sum_k W[j,k] x[b,k].
// 384 blocks x 1024 thr (16 waves). Block = one 16x16 (j,b) tile; wave w
// covers k8 in [w*40, (w+1)*40) = 10 MFMA (2 indep chains). Operands loaded
// DIRECTLY from fp32 global (k-contiguous rows -> 2 x float4 per lane) and
// cvt to bf16 in-register. LDS reduce over 16 waves; epilogue writes
// dtrP (bf16 packed) / Bc / Cc. No k_prep, no k_red1, no partials.
// ---------------------------------------------------------------------------
__global__ __launch_bounds__(1024) void k_g1f(
    const float* __restrict__ x, const float* __restrict__ Wdtr,
    const float* __restrict__ WB, const float* __restrict__ WC,
    char* __restrict__ ws)
{
  __shared__ float4 red[16][64];   // [wave][lane] = f32x4 acc

  const int t  = threadIdx.x;
  const int w  = t >> 6;
  const int l  = t & 63;
  const int jt = blockIdx.x >> 5;        // 0..11
  const int bt = blockIdx.x & 31;        // 0..31
  const int j0 = jt * 16, b0 = bt * 16;

  const int lg = l >> 4, lr = l & 15;

  const float* Wrow;
  if (jt < 10)       Wrow = Wdtr + (size_t)(j0 + lr) * DIN;
  else if (jt == 10) Wrow = WB   + (size_t)(j0 - 160 + lr) * DIN;
  else               Wrow = WC   + (size_t)(j0 - 176 + lr) * DIN;
  const float* xrow = x + (size_t)(b0 + lr) * DIN;

  f32x4 a0 = {0.f, 0.f, 0.f, 0.f}, a1 = a0;

#pragma unroll
  for (int s = 0; s < 5; ++s) {
    const int k0 = (w * 40 + s * 8 + lg) * 8;        // chain 0
    const int k1 = k0 + 32;                          // chain 1 (k8 + 4)
    const float4 wa0 = *(const float4*)(Wrow + k0);
    const float4 wa1 = *(const float4*)(Wrow + k0 + 4);
    const float4 xa0 = *(const float4*)(xrow + k0);
    const float4 xa1 = *(const float4*)(xrow + k0 + 4);
    const float4 wb0 = *(const float4*)(Wrow + k1);
    const float4 wb1 = *(const float4*)(Wrow + k1 + 4);
    const float4 xb0 = *(const float4*)(xrow + k1);
    const float4 xb1 = *(const float4*)(xrow + k1 + 4);
    a0 = __builtin_amdgcn_mfma_f32_16x16x32_bf16(cvt8(wa0, wa1), cvt8(xa0, xa1), a0, 0, 0, 0);
    a1 = __builtin_amdgcn_mfma_f32_16x16x32_bf16(cvt8(wb0, wb1), cvt8(xb0, xb1), a1, 0, 0, 0);
  }

  red[w][l] = (float4){a0[0] + a1[0], a0[1] + a1[1], a0[2] + a1[2], a0[3] + a1[3]};
  __syncthreads();

  if (t < 256) {
    const int ll = t >> 2, r = t & 3;
    const float* rp = (const float*)red;
    float s = 0.f;
#pragma unroll
    for (int ww = 0; ww < 16; ++ww)
      s += rp[(ww * 64 + ll) * 4 + r];

    // D row = j0 + (ll>>4)*4 + r, col = b0 + (ll&15)   (verified mapping)
    const int j = j0 + (ll >> 4) * 4 + r;
    const int b = b0 + (ll & 15);
    if (jt < 10) {
      unsigned short* dtrP = (unsigned short*)(ws + OFF_DTRP);
      dtrP[((size_t)(j >> 3) * 512 + b) * 8 + (j & 7)] = f2bf(s);
    } else if (jt == 10) {
      ((float*)(ws + OFF_B))[(size_t)b * DST + (j - 160)] = s;
    } else {
      ((float*)(ws + OFF_C))[(size_t)b * DST + (j - 176)] = s;
    }
  }
}

// ---------------------------------------------------------------------------
// k_g2y: FUSED dt-GEMM + softplus + state update + y. Wdt loaded directly
// from fp32 global (cvt in-register); dtrP bf16 from k_g1f. 2560 blocks.
// ---------------------------------------------------------------------------
__global__ __launch_bounds__(256) void k_g2y(
    const float* __restrict__ Wdt, const float* __restrict__ bdt,
    const float* __restrict__ A,   const float* __restrict__ Dp,
    const float* __restrict__ x,   const float* __restrict__ h,
    float* __restrict__ y,         char* __restrict__ ws)
{
  __shared__ float sDT[4][16][17];
  __shared__ float sB[4][16][16];
  __shared__ float sC[4][16][16];
  __shared__ float sX[4][16][16];

  const int w = threadIdx.x >> 6;
  const int l = threadIdx.x & 63;
  const int wid = blockIdx.x * 4 + w;
  const int dtile = wid % 320, btile = wid / 320;
  const int d0 = dtile * 16, b0 = btile * 16;

  const bf16x8* dtrPv = (const bf16x8*)(ws + OFF_DTRP);
  const float*  Bc    = (const float*)(ws + OFF_B);
  const float*  Cc    = (const float*)(ws + OFF_C);

  *(float4*)&((float*)sB[w])[l * 4] = *(const float4*)&Bc[b0 * DST + l * 4];
  *(float4*)&((float*)sC[w])[l * 4] = *(const float4*)&Cc[b0 * DST + l * 4];
  {
    const int xr = l >> 2, xc = (l & 3) * 4;
    *(float4*)&sX[w][xr][xc] = *(const float4*)&x[(size_t)(b0 + xr) * DIN + d0 + xc];
  }

  const int lg = l >> 4, lr = l & 15;
  const float* wrow = Wdt + (size_t)(d0 + lr) * RK;

  f32x4 acc = {0.f, 0.f, 0.f, 0.f};
#pragma unroll
  for (int s = 0; s < 5; ++s) {
    const int k8 = s * 4 + lg;
    const bf16x8 av = dtrPv[(size_t)k8 * 512 + b0 + lr];
    const float4 f0 = *(const float4*)(wrow + k8 * 8);
    const float4 f1 = *(const float4*)(wrow + k8 * 8 + 4);
    acc = __builtin_amdgcn_mfma_f32_16x16x32_bf16(av, cvt8(f0, f1), acc, 0, 0, 0);
  }
  const float bias = bdt[d0 + lr];
#pragma unroll
  for (int r = 0; r < 4; ++r) {
    const float pre = acc[r] + bias;   // dt for (b=b0+lg*4+r, d=d0+lr)
    sDT[w][lg * 4 + r][lr] = (pre > 20.f) ? pre : log1pf(__expf(pre));
  }
  __syncthreads();

  const int q = l & 3;
  const int Q = l >> 2;
  const int d = d0 + Q;
  const float4 A4 = *(const float4*)(A + (size_t)d * DST + q * 4);
  const float  Dv = Dp[d];

  const float* hp = h + ((size_t)b0 * DIN + d) * DST + q * 4;
  float* yp = y + (size_t)b0 * DIN + d;

  float4 hbuf[4];
#pragma unroll
  for (int j = 0; j < 4; ++j)
    hbuf[j] = *(const float4*)(hp + (size_t)j * (DIN * DST));

#pragma unroll
  for (int j = 0; j < 16; ++j) {
    const float4 h4 = hbuf[j & 3];
    if (j + 4 < 16)
      hbuf[j & 3] = *(const float4*)(hp + (size_t)(j + 4) * (DIN * DST));

    const float dtv = sDT[w][j][Q];
    const float xv  = sX[w][j][Q];
    const float dtx = dtv * xv;
    const float4 B4 = *(const float4*)&sB[w][j][q * 4];
    const float4 C4 = *(const float4*)&sC[w][j][q * 4];

    const float dA0 = __expf(A4.x * dtv);
    const float dA1 = __expf(A4.y * dtv);
    const float dA2 = __expf(A4.z * dtv);
    const float dA3 = __expf(A4.w * dtv);
    const float hn0 = fmaf(dA0, h4.x, dtx * B4.x);
    const float hn1 = fmaf(dA1, h4.y, dtx * B4.y);
    const float hn2 = fmaf(dA2, h4.z, dtx * B4.z);
    const float hn3 = fmaf(dA3, h4.w, dtx * B4.w);
    float p = hn0 * C4.x + hn1 * C4.y + hn2 * C4.z + hn3 * C4.w;

    p += __shfl_xor(p, 1);
    p += __shfl_xor(p, 2);
    if (q == 0) yp[(size_t)j * DIN] = fmaf(Dv, xv, p);
  }
}

extern "C" void kernel_launch(void* const* d_in, const int* in_sizes, int n_in,
                              void* d_out, int out_size, void* d_ws, size_t ws_size,
                              hipStream_t stream) {
  const float* x    = (const float*)d_in[0];
  const float* Wdtr = (const float*)d_in[1];
  const float* Wdt  = (const float*)d_in[2];
  const float* bdt  = (const float*)d_in[3];
  const float* WB   = (const float*)d_in[4];
  const float* WC   = (const float*)d_in[5];
  const float* A    = (const float*)d_in[6];
  const float* Dp   = (const float*)d_in[7];
  const float* h    = (const float*)d_in[8];
  float* y = (float*)d_out;
  char* ws = (char*)d_ws;

  k_g1f<<<dim3(384), 1024, 0, stream>>>(x, Wdtr, WB, WC, ws);
  k_g2y<<<dim3(2560), 256, 0, stream>>>(Wdt, bdt, A, Dp, x, h, y, ws);
}

// Round 12
// 55.928 us; speedup vs baseline: 1.7465x; 1.3154x over previous
//
#include <hip/hip_runtime.h>
#include <math.h>

#define BATCH 512
#define DIN   5120
#define DST   16
#define RK    160
#define NJ    192     // 160 dt_rank + 16 B + 16 C
#define NZ1   16      // GEMM1 split-K slices

typedef __attribute__((ext_vector_type(8))) __bf16 bf16x8;
typedef __attribute__((ext_vector_type(4))) float f32x4;
typedef __attribute__((ext_vector_type(8))) unsigned short ushort8;

// ws byte offsets (all 16B aligned)
#define OFF_XP    0u          // xP   [640 k8][512 b][8]  bf16
#define OFF_WP    5242880u    // WP   [640 k8][192 j][8]  bf16
#define OFF_WDTP  7208960u    // WdtP [20 k8][5120 d][8]  bf16
#define OFF_PART  8847360u    // part1[6144 task][256]    f32
#define OFF_DTRP  15138816u   // dtrP [20 k8][512 b][8]   bf16
#define OFF_B     15302656u   // Bc   [512][16] f32
#define OFF_C     15335424u   // Cc   [512][16] f32

__device__ __forceinline__ unsigned short f2bf(float f) {
  unsigned int u = __float_as_uint(f);
  u = (u + 0x7FFFu + ((u >> 16) & 1u)) >> 16;   // RNE
  return (unsigned short)u;
}

// ---------------------------------------------------------------------------
// k_prep2: pack bf16 operands via LDS tile-transpose so BOTH global reads and
// global writes are coalesced (R9's k_prep had 16B writes at 8KB stride).
//  blocks   0..159: xP   tiles 64b x 256k   (8 x 20)
//  blocks 160..219: WP   tiles 64j x 256k   (3 x 20)
//  blocks 220..299: WdtP tiles 64d x 160k   (80)
// ---------------------------------------------------------------------------
__global__ __launch_bounds__(256) void k_prep2(
    const float* __restrict__ x, const float* __restrict__ Wdtr,
    const float* __restrict__ WB, const float* __restrict__ WC,
    const float* __restrict__ Wdt, char* __restrict__ ws)
{
  __shared__ unsigned short sT[64 * 264];   // padded rows (8-way worst LDS conflict)
  const int t = threadIdx.x;
  const int bid = blockIdx.x;

  if (bid < 160) {            // ---- job A: xP ----
    const int bt = bid & 7, kt = bid >> 3;      // kt 0..19
    const int b0 = bt * 64, k0 = kt * 256;
#pragma unroll
    for (int i = 0; i < 16; ++i) {
      const int f = i * 256 + t;                // 0..4095
      const int r = f >> 6, c = f & 63;
      const float4 v = *(const float4*)&x[(size_t)(b0 + r) * DIN + k0 + c * 4];
      unsigned short* p = &sT[r * 264 + c * 4];
      p[0] = f2bf(v.x); p[1] = f2bf(v.y); p[2] = f2bf(v.z); p[3] = f2bf(v.w);
    }
    __syncthreads();
    ushort8* xP = (ushort8*)(ws + OFF_XP);
#pragma unroll
    for (int i = 0; i < 8; ++i) {
      const int o = i * 256 + t;                // 0..2047
      const int k8l = o >> 6, bl = o & 63;
      const unsigned short* p = &sT[bl * 264 + k8l * 8];
      ushort8 v;
#pragma unroll
      for (int e = 0; e < 8; ++e) v[e] = p[e];
      xP[(size_t)(kt * 32 + k8l) * 512 + b0 + bl] = v;
    }
  } else if (bid < 220) {     // ---- job B: WP ----
    const int bb = bid - 160;
    const int jt = bb % 3, kt = bb / 3;         // kt 0..19
    const int j0 = jt * 64, k0 = kt * 256;
#pragma unroll
    for (int i = 0; i < 16; ++i) {
      const int f = i * 256 + t;
      const int r = f >> 6, c = f & 63;
      const int j = j0 + r;
      const float* row;
      if (j < RK)            row = Wdtr + (size_t)j * DIN;
      else if (j < RK + DST) row = WB   + (size_t)(j - RK) * DIN;
      else                   row = WC   + (size_t)(j - RK - DST) * DIN;
      const float4 v = *(const float4*)&row[k0 + c * 4];
      unsigned short* p = &sT[r * 264 + c * 4];
      p[0] = f2bf(v.x); p[1] = f2bf(v.y); p[2] = f2bf(v.z); p[3] = f2bf(v.w);
    }
    __syncthreads();
    ushort8* WPo = (ushort8*)(ws + OFF_WP);
#pragma unroll
    for (int i = 0; i < 8; ++i) {
      const int o = i * 256 + t;
      const int k8l = o >> 6, jl = o & 63;
      const unsigned short* p = &sT[jl * 264 + k8l * 8];
      ushort8 v;
#pragma unroll
      for (int e = 0; e < 8; ++e) v[e] = p[e];
      WPo[(size_t)(kt * 32 + k8l) * 192 + j0 + jl] = v;
    }
  } else {                    // ---- job C: WdtP ----
    const int d0 = (bid - 220) * 64;
#pragma unroll
    for (int i = 0; i < 10; ++i) {
      const int f = i * 256 + t;                // 0..2559
      const int r = f / 40, c = f - r * 40;     // 40 float4 per row
      const float4 v = *(const float4*)&Wdt[(size_t)(d0 + r) * RK + c * 4];
      unsigned short* p = &sT[r * 168 + c * 4];
      p[0] = f2bf(v.x); p[1] = f2bf(v.y); p[2] = f2bf(v.z); p[3] = f2bf(v.w);
    }
    __syncthreads();
    ushort8* WdtPo = (ushort8*)(ws + OFF_WDTP);
#pragma unroll
    for (int i = 0; i < 5; ++i) {
      const int o = i * 256 + t;                // 0..1279
      const int k8l = o >> 6, dl = o & 63;
      const unsigned short* p = &sT[dl * 168 + k8l * 8];
      ushort8 v;
#pragma unroll
      for (int e = 0; e < 8; ++e) v[e] = p[e];
      WdtPo[(size_t)k8l * 5120 + d0 + dl] = v;
    }
  }
}

// ---------------------------------------------------------------------------
// k_g1: GEMM1 via MFMA. P[j,b] = sum_k W[j,k] x[b,k]. Split-K NZ1=16.
// One 16x16 tile per wave, 10 MFMA steps of k=32. 1536 blocks. (R9 form)
// ---------------------------------------------------------------------------
__global__ __launch_bounds__(256) void k_g1(char* __restrict__ ws)
{
  const int wid  = blockIdx.x * 4 + (threadIdx.x >> 6);
  const int l    = threadIdx.x & 63;
  const int z    = wid / 384;
  const int rem  = wid - z * 384;
  const int jt   = rem >> 5;
  const int bt   = rem & 31;
  const int j0   = jt * 16, b0 = bt * 16;

  const bf16x8* WPv = (const bf16x8*)(ws + OFF_WP);
  const bf16x8* xPv = (const bf16x8*)(ws + OFF_XP);
  float* part = (float*)(ws + OFF_PART);

  const int lg = l >> 4, lr = l & 15;
  f32x4 acc = {0.f, 0.f, 0.f, 0.f};

#pragma unroll 2
  for (int s = 0; s < 10; ++s) {
    const int k8 = z * 40 + s * 4 + lg;
    const bf16x8 av = WPv[(size_t)k8 * 192 + j0 + lr];
    const bf16x8 bv = xPv[(size_t)k8 * 512 + b0 + lr];
    acc = __builtin_amdgcn_mfma_f32_16x16x32_bf16(av, bv, acc, 0, 0, 0);
  }

  float* pb = part + (size_t)wid * 256;
#pragma unroll
  for (int r = 0; r < 4; ++r)
    pb[(lg * 4 + r) * 16 + lr] = acc[r];
}

// ---------------------------------------------------------------------------
// k_red1: sum 16 slices -> dtrP (bf16 packed) / Bc / Cc. 384 blocks. (R9)
// ---------------------------------------------------------------------------
__global__ __launch_bounds__(256) void k_red1(char* __restrict__ ws)
{
  const int e = blockIdx.x * 256 + threadIdx.x;   // (j, b)
  const int j = e >> 9, b = e & 511;
  const int jt = j >> 4, jr = j & 15, bt = b >> 4, bc = b & 15;

  const float* part = (const float*)(ws + OFF_PART);
  float s = 0.f;
#pragma unroll
  for (int z = 0; z < NZ1; ++z)
    s += part[((size_t)(z * 384 + jt * 32 + bt) << 8) + jr * 16 + bc];

  if (j < RK) {
    unsigned short* dtrP = (unsigned short*)(ws + OFF_DTRP);
    dtrP[((size_t)(j >> 3) * 512 + b) * 8 + (j & 7)] = f2bf(s);
  } else if (j < RK + DST) {
    ((float*)(ws + OFF_B))[(size_t)b * DST + (j - RK)] = s;
  } else {
    ((float*)(ws + OFF_C))[(size_t)b * DST + (j - RK - DST)] = s;
  }
}

// ---------------------------------------------------------------------------
// k_g2y: FUSED dt-GEMM + softplus + state update + y. (R9 form, unchanged)
// ---------------------------------------------------------------------------
__global__ __launch_bounds__(256) void k_g2y(
    const float* __restrict__ bdt, const float* __restrict__ A,
    const float* __restrict__ Dp,  const float* __restrict__ x,
    const float* __restrict__ h,   float* __restrict__ y,
    char* __restrict__ ws)
{
  __shared__ float sDT[4][16][17];
  __shared__ float sB[4][16][16];
  __shared__ float sC[4][16][16];
  __shared__ float sX[4][16][16];

  const int w = threadIdx.x >> 6;
  const int l = threadIdx.x & 63;
  const int wid = blockIdx.x * 4 + w;
  const int dtile = wid % 320, btile = wid / 320;
  const int d0 = dtile * 16, b0 = btile * 16;

  const bf16x8* dtrPv = (const bf16x8*)(ws + OFF_DTRP);
  const bf16x8* WdtPv = (const bf16x8*)(ws + OFF_WDTP);
  const float*  Bc    = (const float*)(ws + OFF_B);
  const float*  Cc    = (const float*)(ws + OFF_C);

  *(float4*)&((float*)sB[w])[l * 4] = *(const float4*)&Bc[b0 * DST + l * 4];
  *(float4*)&((float*)sC[w])[l * 4] = *(const float4*)&Cc[b0 * DST + l * 4];
  {
    const int xr = l >> 2, xc = (l & 3) * 4;
    *(float4*)&sX[w][xr][xc] = *(const float4*)&x[(size_t)(b0 + xr) * DIN + d0 + xc];
  }

  const int lg = l >> 4, lr = l & 15;
  f32x4 acc = {0.f, 0.f, 0.f, 0.f};
#pragma unroll
  for (int s = 0; s < 5; ++s) {
    const int k8 = s * 4 + lg;
    const bf16x8 av = dtrPv[(size_t)k8 * 512 + b0 + lr];
    const bf16x8 bv = WdtPv[(size_t)k8 * 5120 + d0 + lr];
    acc = __builtin_amdgcn_mfma_f32_16x16x32_bf16(av, bv, acc, 0, 0, 0);
  }
  const float bias = bdt[d0 + lr];
#pragma unroll
  for (int r = 0; r < 4; ++r) {
    const float pre = acc[r] + bias;
    sDT[w][lg * 4 + r][lr] = (pre > 20.f) ? pre : log1pf(__expf(pre));
  }
  __syncthreads();

  const int q = l & 3;
  const int Q = l >> 2;
  const int d = d0 + Q;
  const float4 A4 = *(const float4*)(A + (size_t)d * DST + q * 4);
  const float  Dv = Dp[d];

  const float* hp = h + ((size_t)b0 * DIN + d) * DST + q * 4;
  float* yp = y + (size_t)b0 * DIN + d;

  float4 hbuf[4];
#pragma unroll
  for (int j = 0; j < 4; ++j)
    hbuf[j] = *(const float4*)(hp + (size_t)j * (DIN * DST));

#pragma unroll
  for (int j = 0; j < 16; ++j) {
    const float4 h4 = hbuf[j & 3];
    if (j + 4 < 16)
      hbuf[j & 3] = *(const float4*)(hp + (size_t)(j + 4) * (DIN * DST));

    const float dtv = sDT[w][j][Q];
    const float xv  = sX[w][j][Q];
    const float dtx = dtv * xv;
    const float4 B4 = *(const float4*)&sB[w][j][q * 4];
    const float4 C4 = *(const float4*)&sC[w][j][q * 4];

    const float dA0 = __expf(A4.x * dtv);
    const float dA1 = __expf(A4.y * dtv);
    const float dA2 = __expf(A4.z * dtv);
    const float dA3 = __expf(A4.w * dtv);
    const float hn0 = fmaf(dA0, h4.x, dtx * B4.x);
    const float hn1 = fmaf(dA1, h4.y, dtx * B4.y);
    const float hn2 = fmaf(dA2, h4.z, dtx * B4.z);
    const float hn3 = fmaf(dA3, h4.w, dtx * B4.w);
    float p = hn0 * C4.x + hn1 * C4.y + hn2 * C4.z + hn3 * C4.w;

    p += __shfl_xor(p, 1);
    p += __shfl_xor(p, 2);
    if (q == 0) yp[(size_t)j * DIN] = fmaf(Dv, xv, p);
  }
}

extern "C" void kernel_launch(void* const* d_in, const int* in_sizes, int n_in,
                              void* d_out, int out_size, void* d_ws, size_t ws_size,
                              hipStream_t stream) {
  const float* x    = (const float*)d_in[0];
  const float* Wdtr = (const float*)d_in[1];
  const float* Wdt  = (const float*)d_in[2];
  const float* bdt  = (const float*)d_in[3];
  const float* WB   = (const float*)d_in[4];
  const float* WC   = (const float*)d_in[5];
  const float* A    = (const float*)d_in[6];
  const float* Dp   = (const float*)d_in[7];
  const float* h    = (const float*)d_in[8];
  float* y = (float*)d_out;
  char* ws = (char*)d_ws;

  k_prep2<<<dim3(300), 256, 0, stream>>>(x, Wdtr, WB, WC, Wdt, ws);
  k_g1<<<dim3(1536), 256, 0, stream>>>(ws);
  k_red1<<<dim3(384), 256, 0, stream>>>(ws);
  k_g2y<<<dim3(2560), 256, 0, stream>>>(bdt, A, Dp, x, h, y, ws);
}

// Round 13
// 54.136 us; speedup vs baseline: 1.8043x; 1.0331x over previous
//
#include <hip/hip_runtime.h>
#include <math.h>

#define BATCH 512
#define DIN   5120
#define DST   16
#define RK    160
#define NJ    192     // 160 dt_rank + 16 B + 16 C

typedef __attribute__((ext_vector_type(8))) __bf16 bf16x8;
typedef __attribute__((ext_vector_type(4))) float f32x4;
typedef __attribute__((ext_vector_type(8))) unsigned short ushort8;

// ws byte offsets (all 16B aligned)
#define OFF_XP    0u          // xP   [640 k8][512 b][8]  bf16
#define OFF_WP    5242880u    // WP   [640 k8][192 j][8]  bf16
#define OFF_WDTP  7208960u    // WdtP [20 k8][5120 d][8]  bf16
#define OFF_DTRP  8847360u    // dtrP [20 k8][512 b][8]   bf16
#define OFF_B     9011200u    // Bc   [512][16] f32
#define OFF_C     9043968u    // Cc   [512][16] f32

__device__ __forceinline__ unsigned short f2bf(float f) {
  unsigned int u = __float_as_uint(f);
  u = (u + 0x7FFFu + ((u >> 16) & 1u)) >> 16;   // RNE
  return (unsigned short)u;
}

// ---------------------------------------------------------------------------
// k_prep2: pack bf16 operands via LDS tile-transpose (R12 form, unchanged).
// ---------------------------------------------------------------------------
__global__ __launch_bounds__(256) void k_prep2(
    const float* __restrict__ x, const float* __restrict__ Wdtr,
    const float* __restrict__ WB, const float* __restrict__ WC,
    const float* __restrict__ Wdt, char* __restrict__ ws)
{
  __shared__ unsigned short sT[64 * 264];
  const int t = threadIdx.x;
  const int bid = blockIdx.x;

  if (bid < 160) {            // ---- job A: xP ----
    const int bt = bid & 7, kt = bid >> 3;
    const int b0 = bt * 64, k0 = kt * 256;
#pragma unroll
    for (int i = 0; i < 16; ++i) {
      const int f = i * 256 + t;
      const int r = f >> 6, c = f & 63;
      const float4 v = *(const float4*)&x[(size_t)(b0 + r) * DIN + k0 + c * 4];
      unsigned short* p = &sT[r * 264 + c * 4];
      p[0] = f2bf(v.x); p[1] = f2bf(v.y); p[2] = f2bf(v.z); p[3] = f2bf(v.w);
    }
    __syncthreads();
    ushort8* xP = (ushort8*)(ws + OFF_XP);
#pragma unroll
    for (int i = 0; i < 8; ++i) {
      const int o = i * 256 + t;
      const int k8l = o >> 6, bl = o & 63;
      const unsigned short* p = &sT[bl * 264 + k8l * 8];
      ushort8 v;
#pragma unroll
      for (int e = 0; e < 8; ++e) v[e] = p[e];
      xP[(size_t)(kt * 32 + k8l) * 512 + b0 + bl] = v;
    }
  } else if (bid < 220) {     // ---- job B: WP ----
    const int bb = bid - 160;
    const int jt = bb % 3, kt = bb / 3;
    const int j0 = jt * 64, k0 = kt * 256;
#pragma unroll
    for (int i = 0; i < 16; ++i) {
      const int f = i * 256 + t;
      const int r = f >> 6, c = f & 63;
      const int j = j0 + r;
      const float* row;
      if (j < RK)            row = Wdtr + (size_t)j * DIN;
      else if (j < RK + DST) row = WB   + (size_t)(j - RK) * DIN;
      else                   row = WC   + (size_t)(j - RK - DST) * DIN;
      const float4 v = *(const float4*)&row[k0 + c * 4];
      unsigned short* p = &sT[r * 264 + c * 4];
      p[0] = f2bf(v.x); p[1] = f2bf(v.y); p[2] = f2bf(v.z); p[3] = f2bf(v.w);
    }
    __syncthreads();
    ushort8* WPo = (ushort8*)(ws + OFF_WP);
#pragma unroll
    for (int i = 0; i < 8; ++i) {
      const int o = i * 256 + t;
      const int k8l = o >> 6, jl = o & 63;
      const unsigned short* p = &sT[jl * 264 + k8l * 8];
      ushort8 v;
#pragma unroll
      for (int e = 0; e < 8; ++e) v[e] = p[e];
      WPo[(size_t)(kt * 32 + k8l) * 192 + j0 + jl] = v;
    }
  } else {                    // ---- job C: WdtP ----
    const int d0 = (bid - 220) * 64;
#pragma unroll
    for (int i = 0; i < 10; ++i) {
      const int f = i * 256 + t;
      const int r = f / 40, c = f - r * 40;
      const float4 v = *(const float4*)&Wdt[(size_t)(d0 + r) * RK + c * 4];
      unsigned short* p = &sT[r * 168 + c * 4];
      p[0] = f2bf(v.x); p[1] = f2bf(v.y); p[2] = f2bf(v.z); p[3] = f2bf(v.w);
    }
    __syncthreads();
    ushort8* WdtPo = (ushort8*)(ws + OFF_WDTP);
#pragma unroll
    for (int i = 0; i < 5; ++i) {
      const int o = i * 256 + t;
      const int k8l = o >> 6, dl = o & 63;
      const unsigned short* p = &sT[dl * 168 + k8l * 8];
      ushort8 v;
#pragma unroll
      for (int e = 0; e < 8; ++e) v[e] = p[e];
      WdtPo[(size_t)k8l * 5120 + d0 + dl] = v;
    }
  }
}

// ---------------------------------------------------------------------------
// k_g1f2: GEMM1 with split-K INSIDE the block (R10 structure + R12 packed
// operands). 384 blocks x 1024 thr; wave w = K-slice [w*40,(w+1)*40) k8,
// 10 MFMA steps on coalesced packed fragments. LDS reduce over 16 waves;
// epilogue writes dtrP / Bc / Cc directly. No partials, no k_red1.
// ---------------------------------------------------------------------------
__global__ __launch_bounds__(1024) void k_g1f2(char* __restrict__ ws)
{
  __shared__ float4 red[16][64];

  const int t = threadIdx.x;
  const int w = t >> 6, l = t & 63;
  const int jt = blockIdx.x >> 5, bt = blockIdx.x & 31;
  const int j0 = jt * 16, b0 = bt * 16;

  const bf16x8* WPv = (const bf16x8*)(ws + OFF_WP);
  const bf16x8* xPv = (const bf16x8*)(ws + OFF_XP);

  const int lg = l >> 4, lr = l & 15;
  f32x4 acc = {0.f, 0.f, 0.f, 0.f};

#pragma unroll
  for (int s = 0; s < 10; ++s) {
    const int k8 = w * 40 + s * 4 + lg;
    const bf16x8 av = WPv[(size_t)k8 * 192 + j0 + lr];
    const bf16x8 bv = xPv[(size_t)k8 * 512 + b0 + lr];
    acc = __builtin_amdgcn_mfma_f32_16x16x32_bf16(av, bv, acc, 0, 0, 0);
  }

  red[w][l] = (float4){acc[0], acc[1], acc[2], acc[3]};
  __syncthreads();

  if (t < 256) {
    const int ll = t >> 2, r = t & 3;
    const float* rp = (const float*)red;
    float s = 0.f;
#pragma unroll
    for (int ww = 0; ww < 16; ++ww)
      s += rp[(ww * 64 + ll) * 4 + r];

    // D row = j0 + (ll>>4)*4 + r, col = b0 + (ll&15)  (verified R10/R11)
    const int j = j0 + (ll >> 4) * 4 + r;
    const int b = b0 + (ll & 15);
    if (jt < 10) {
      unsigned short* dtrP = (unsigned short*)(ws + OFF_DTRP);
      dtrP[((size_t)(j >> 3) * 512 + b) * 8 + (j & 7)] = f2bf(s);
    } else if (jt == 10) {
      ((float*)(ws + OFF_B))[(size_t)b * DST + (j - 160)] = s;
    } else {
      ((float*)(ws + OFF_C))[(size_t)b * DST + (j - 176)] = s;
    }
  }
}

// ---------------------------------------------------------------------------
// k_g2y: FUSED dt-GEMM + softplus + state update + y. (R12 form, unchanged)
// ---------------------------------------------------------------------------
__global__ __launch_bounds__(256) void k_g2y(
    const float* __restrict__ bdt, const float* __restrict__ A,
    const float* __restrict__ Dp,  const float* __restrict__ x,
    const float* __restrict__ h,   float* __restrict__ y,
    char* __restrict__ ws)
{
  __shared__ float sDT[4][16][17];
  __shared__ float sB[4][16][16];
  __shared__ float sC[4][16][16];
  __shared__ float sX[4][16][16];

  const int w = threadIdx.x >> 6;
  const int l = threadIdx.x & 63;
  const int wid = blockIdx.x * 4 + w;
  const int dtile = wid % 320, btile = wid / 320;
  const int d0 = dtile * 16, b0 = btile * 16;

  const bf16x8* dtrPv = (const bf16x8*)(ws + OFF_DTRP);
  const bf16x8* WdtPv = (const bf16x8*)(ws + OFF_WDTP);
  const float*  Bc    = (const float*)(ws + OFF_B);
  const float*  Cc    = (const float*)(ws + OFF_C);

  *(float4*)&((float*)sB[w])[l * 4] = *(const float4*)&Bc[b0 * DST + l * 4];
  *(float4*)&((float*)sC[w])[l * 4] = *(const float4*)&Cc[b0 * DST + l * 4];
  {
    const int xr = l >> 2, xc = (l & 3) * 4;
    *(float4*)&sX[w][xr][xc] = *(const float4*)&x[(size_t)(b0 + xr) * DIN + d0 + xc];
  }

  const int lg = l >> 4, lr = l & 15;
  f32x4 acc = {0.f, 0.f, 0.f, 0.f};
#pragma unroll
  for (int s = 0; s < 5; ++s) {
    const int k8 = s * 4 + lg;
    const bf16x8 av = dtrPv[(size_t)k8 * 512 + b0 + lr];
    const bf16x8 bv = WdtPv[(size_t)k8 * 5120 + d0 + lr];
    acc = __builtin_amdgcn_mfma_f32_16x16x32_bf16(av, bv, acc, 0, 0, 0);
  }
  const float bias = bdt[d0 + lr];
#pragma unroll
  for (int r = 0; r < 4; ++r) {
    const float pre = acc[r] + bias;
    sDT[w][lg * 4 + r][lr] = (pre > 20.f) ? pre : log1pf(__expf(pre));
  }
  __syncthreads();

  const int q = l & 3;
  const int Q = l >> 2;
  const int d = d0 + Q;
  const float4 A4 = *(const float4*)(A + (size_t)d * DST + q * 4);
  const float  Dv = Dp[d];

  const float* hp = h + ((size_t)b0 * DIN + d) * DST + q * 4;
  float* yp = y + (size_t)b0 * DIN + d;

  float4 hbuf[4];
#pragma unroll
  for (int j = 0; j < 4; ++j)
    hbuf[j] = *(const float4*)(hp + (size_t)j * (DIN * DST));

#pragma unroll
  for (int j = 0; j < 16; ++j) {
    const float4 h4 = hbuf[j & 3];
    if (j + 4 < 16)
      hbuf[j & 3] = *(const float4*)(hp + (size_t)(j + 4) * (DIN * DST));

    const float dtv = sDT[w][j][Q];
    const float xv  = sX[w][j][Q];
    const float dtx = dtv * xv;
    const float4 B4 = *(const float4*)&sB[w][j][q * 4];
    const float4 C4 = *(const float4*)&sC[w][j][q * 4];

    const float dA0 = __expf(A4.x * dtv);
    const float dA1 = __expf(A4.y * dtv);
    const float dA2 = __expf(A4.z * dtv);
    const float dA3 = __expf(A4.w * dtv);
    const float hn0 = fmaf(dA0, h4.x, dtx * B4.x);
    const float hn1 = fmaf(dA1, h4.y, dtx * B4.y);
    const float hn2 = fmaf(dA2, h4.z, dtx * B4.z);
    const float hn3 = fmaf(dA3, h4.w, dtx * B4.w);
    float p = hn0 * C4.x + hn1 * C4.y + hn2 * C4.z + hn3 * C4.w;

    p += __shfl_xor(p, 1);
    p += __shfl_xor(p, 2);
    if (q == 0) yp[(size_t)j * DIN] = fmaf(Dv, xv, p);
  }
}

extern "C" void kernel_launch(void* const* d_in, const int* in_sizes, int n_in,
                              void* d_out, int out_size, void* d_ws, size_t ws_size,
                              hipStream_t stream) {
  const float* x    = (const float*)d_in[0];
  const float* Wdtr = (const float*)d_in[1];
  const float* Wdt  = (const float*)d_in[2];
  const float* bdt  = (const float*)d_in[3];
  const float* WB   = (const float*)d_in[4];
  const float* WC   = (const float*)d_in[5];
  const float* A    = (const float*)d_in[6];
  const float* Dp   = (const float*)d_in[7];
  const float* h    = (const float*)d_in[8];
  float* y = (float*)d_out;
  char* ws = (char*)d_ws;

  k_prep2<<<dim3(300), 256, 0, stream>>>(x, Wdtr, WB, WC, Wdt, ws);
  k_g1f2<<<dim3(384), 1024, 0, stream>>>(ws);
  k_g2y<<<dim3(2560), 256, 0, stream>>>(bdt, A, Dp, x, h, y, ws);
}

// Round 15
// 51.715 us; speedup vs baseline: 1.8888x; 1.0468x over previous
//
#include <hip/hip_runtime.h>
#include <math.h>

#define BATCH 512
#define DIN   5120
#define DST   16
#define RK    160
#define NJ    192     // 160 dt_rank + 16 B + 16 C

typedef __attribute__((ext_vector_type(8))) __bf16 bf16x8;
typedef __attribute__((ext_vector_type(4))) float f32x4;
typedef __attribute__((ext_vector_type(8))) unsigned short ushort8;

// ws byte offsets (all 16B aligned)
#define OFF_XP    0u          // xP   [640 k8][512 b][8]  bf16
#define OFF_WP    5242880u    // WP   [640 k8][192 j][8]  bf16
#define OFF_WDTP  7208960u    // WdtP [20 k8][5120 d][8]  bf16
#define OFF_DTRP  8847360u    // dtrP [20 k8][512 b][8]   bf16
#define OFF_B     9011200u    // Bc   [512][16] f32
#define OFF_C     9043968u    // Cc   [512][16] f32

__device__ __forceinline__ unsigned short f2bf(float f) {
  unsigned int u = __float_as_uint(f);
  u = (u + 0x7FFFu + ((u >> 16) & 1u)) >> 16;   // RNE
  return (unsigned short)u;
}

// ---------------------------------------------------------------------------
// k_prep3: bf16 pack via LDS tile-transpose, WIDENED to 960 blocks (vs
// prep2's 300 = 1.2 blocks/CU, latency-bound). k-tiles of 64 for jobs A/B.
//  blocks   0..639: xP   tiles 64b x 64k   (8 b x 80 k)
//  blocks 640..879: WP   tiles 64j x 64k   (3 j x 80 k)
//  blocks 880..959: WdtP tiles 64d x 160k  (80 d)
// Reads fp32 coalesced; writes packed bf16 in contiguous 1KB runs.
// ---------------------------------------------------------------------------
__global__ __launch_bounds__(256) void k_prep3(
    const float* __restrict__ x, const float* __restrict__ Wdtr,
    const float* __restrict__ WB, const float* __restrict__ WC,
    const float* __restrict__ Wdt, char* __restrict__ ws)
{
  __shared__ unsigned short sT[64 * 168];
  const int t = threadIdx.x;
  const int bid = blockIdx.x;

  if (bid < 640) {            // ---- job A: xP ----
    const int bt = bid & 7, kt = bid >> 3;      // kt 0..79
    const int b0 = bt * 64, k0 = kt * 64;
#pragma unroll
    for (int i = 0; i < 4; ++i) {
      const int f = i * 256 + t;                // 0..1023
      const int r = f >> 4, c = f & 15;         // 64 rows x 16 float4
      const float4 v = *(const float4*)&x[(size_t)(b0 + r) * DIN + k0 + c * 4];
      unsigned short* p = &sT[r * 72 + c * 4];
      p[0] = f2bf(v.x); p[1] = f2bf(v.y); p[2] = f2bf(v.z); p[3] = f2bf(v.w);
    }
    __syncthreads();
    ushort8* xP = (ushort8*)(ws + OFF_XP);
#pragma unroll
    for (int i = 0; i < 2; ++i) {
      const int o = i * 256 + t;                // 0..511
      const int k8l = o >> 6, bl = o & 63;
      const unsigned short* p = &sT[bl * 72 + k8l * 8];
      ushort8 v;
#pragma unroll
      for (int e = 0; e < 8; ++e) v[e] = p[e];
      xP[(size_t)(kt * 8 + k8l) * 512 + b0 + bl] = v;
    }
  } else if (bid < 880) {     // ---- job B: WP ----
    const int bb = bid - 640;
    const int jt = bb % 3, kt = bb / 3;         // kt 0..79
    const int j0 = jt * 64, k0 = kt * 64;
#pragma unroll
    for (int i = 0; i < 4; ++i) {
      const int f = i * 256 + t;
      const int r = f >> 4, c = f & 15;
      const int j = j0 + r;
      const float* row;
      if (j < RK)            row = Wdtr + (size_t)j * DIN;
      else if (j < RK + DST) row = WB   + (size_t)(j - RK) * DIN;
      else                   row = WC   + (size_t)(j - RK - DST) * DIN;
      const float4 v = *(const float4*)&row[k0 + c * 4];
      unsigned short* p = &sT[r * 72 + c * 4];
      p[0] = f2bf(v.x); p[1] = f2bf(v.y); p[2] = f2bf(v.z); p[3] = f2bf(v.w);
    }
    __syncthreads();
    ushort8* WPo = (ushort8*)(ws + OFF_WP);
#pragma unroll
    for (int i = 0; i < 2; ++i) {
      const int o = i * 256 + t;
      const int k8l = o >> 6, jl = o & 63;
      const unsigned short* p = &sT[jl * 72 + k8l * 8];
      ushort8 v;
#pragma unroll
      for (int e = 0; e < 8; ++e) v[e] = p[e];
      WPo[(size_t)(kt * 8 + k8l) * 192 + j0 + jl] = v;
    }
  } else {                    // ---- job C: WdtP ----
    const int d0 = (bid - 880) * 64;
#pragma unroll
    for (int i = 0; i < 10; ++i) {
      const int f = i * 256 + t;                // 0..2559
      const int r = f / 40, c = f - r * 40;     // 40 float4 per row
      const float4 v = *(const float4*)&Wdt[(size_t)(d0 + r) * RK + c * 4];
      unsigned short* p = &sT[r * 168 + c * 4];
      p[0] = f2bf(v.x); p[1] = f2bf(v.y); p[2] = f2bf(v.z); p[3] = f2bf(v.w);
    }
    __syncthreads();
    ushort8* WdtPo = (ushort8*)(ws + OFF_WDTP);
#pragma unroll
    for (int i = 0; i < 5; ++i) {
      const int o = i * 256 + t;                // 0..1279
      const int k8l = o >> 6, dl = o & 63;      // k8l 0..19
      const unsigned short* p = &sT[dl * 168 + k8l * 8];
      ushort8 v;
#pragma unroll
      for (int e = 0; e < 8; ++e) v[e] = p[e];
      WdtPo[(size_t)k8l * 5120 + d0 + dl] = v;
    }
  }
}

// ---------------------------------------------------------------------------
// k_g1f2: GEMM1 with split-K inside the block (R13 form, unchanged).
// 384 blocks x 1024 thr; wave w = K-slice, 10 MFMA; LDS reduce; epilogue
// writes dtrP / Bc / Cc directly.
// ---------------------------------------------------------------------------
__global__ __launch_bounds__(1024) void k_g1f2(char* __restrict__ ws)
{
  __shared__ float4 red[16][64];

  const int t = threadIdx.x;
  const int w = t >> 6, l = t & 63;
  const int jt = blockIdx.x >> 5, bt = blockIdx.x & 31;
  const int j0 = jt * 16, b0 = bt * 16;

  const bf16x8* WPv = (const bf16x8*)(ws + OFF_WP);
  const bf16x8* xPv = (const bf16x8*)(ws + OFF_XP);

  const int lg = l >> 4, lr = l & 15;
  f32x4 acc = {0.f, 0.f, 0.f, 0.f};

#pragma unroll
  for (int s = 0; s < 10; ++s) {
    const int k8 = w * 40 + s * 4 + lg;
    const bf16x8 av = WPv[(size_t)k8 * 192 + j0 + lr];
    const bf16x8 bv = xPv[(size_t)k8 * 512 + b0 + lr];
    acc = __builtin_amdgcn_mfma_f32_16x16x32_bf16(av, bv, acc, 0, 0, 0);
  }

  red[w][l] = (float4){acc[0], acc[1], acc[2], acc[3]};
  __syncthreads();

  if (t < 256) {
    const int ll = t >> 2, r = t & 3;
    const float* rp = (const float*)red;
    float s = 0.f;
#pragma unroll
    for (int ww = 0; ww < 16; ++ww)
      s += rp[(ww * 64 + ll) * 4 + r];

    const int j = j0 + (ll >> 4) * 4 + r;
    const int b = b0 + (ll & 15);
    if (jt < 10) {
      unsigned short* dtrP = (unsigned short*)(ws + OFF_DTRP);
      dtrP[((size_t)(j >> 3) * 512 + b) * 8 + (j & 7)] = f2bf(s);
    } else if (jt == 10) {
      ((float*)(ws + OFF_B))[(size_t)b * DST + (j - 160)] = s;
    } else {
      ((float*)(ws + OFF_C))[(size_t)b * DST + (j - 176)] = s;
    }
  }
}

// ---------------------------------------------------------------------------
// k_g2y: FUSED dt-GEMM + softplus + state update + y. (R13 form, unchanged)
// ---------------------------------------------------------------------------
__global__ __launch_bounds__(256) void k_g2y(
    const float* __restrict__ bdt, const float* __restrict__ A,
    const float* __restrict__ Dp,  const float* __restrict__ x,
    const float* __restrict__ h,   float* __restrict__ y,
    char* __restrict__ ws)
{
  __shared__ float sDT[4][16][17];
  __shared__ float sB[4][16][16];
  __shared__ float sC[4][16][16];
  __shared__ float sX[4][16][16];

  const int w = threadIdx.x >> 6;
  const int l = threadIdx.x & 63;
  const int wid = blockIdx.x * 4 + w;
  const int dtile = wid % 320, btile = wid / 320;
  const int d0 = dtile * 16, b0 = btile * 16;

  const bf16x8* dtrPv = (const bf16x8*)(ws + OFF_DTRP);
  const bf16x8* WdtPv = (const bf16x8*)(ws + OFF_WDTP);
  const float*  Bc    = (const float*)(ws + OFF_B);
  const float*  Cc    = (const float*)(ws + OFF_C);

  *(float4*)&((float*)sB[w])[l * 4] = *(const float4*)&Bc[b0 * DST + l * 4];
  *(float4*)&((float*)sC[w])[l * 4] = *(const float4*)&Cc[b0 * DST + l * 4];
  {
    const int xr = l >> 2, xc = (l & 3) * 4;
    *(float4*)&sX[w][xr][xc] = *(const float4*)&x[(size_t)(b0 + xr) * DIN + d0 + xc];
  }

  const int lg = l >> 4, lr = l & 15;
  f32x4 acc = {0.f, 0.f, 0.f, 0.f};
#pragma unroll
  for (int s = 0; s < 5; ++s) {
    const int k8 = s * 4 + lg;
    const bf16x8 av = dtrPv[(size_t)k8 * 512 + b0 + lr];
    const bf16x8 bv = WdtPv[(size_t)k8 * 5120 + d0 + lr];
    acc = __builtin_amdgcn_mfma_f32_16x16x32_bf16(av, bv, acc, 0, 0, 0);
  }
  const float bias = bdt[d0 + lr];
#pragma unroll
  for (int r = 0; r < 4; ++r) {
    const float pre = acc[r] + bias;
    sDT[w][lg * 4 + r][lr] = (pre > 20.f) ? pre : log1pf(__expf(pre));
  }
  __syncthreads();

  const int q = l & 3;
  const int Q = l >> 2;
  const int d = d0 + Q;
  const float4 A4 = *(const float4*)(A + (size_t)d * DST + q * 4);
  const float  Dv = Dp[d];

  const float* hp = h + ((size_t)b0 * DIN + d) * DST + q * 4;
  float* yp = y + (size_t)b0 * DIN + d;

  float4 hbuf[4];
#pragma unroll
  for (int j = 0; j < 4; ++j)
    hbuf[j] = *(const float4*)(hp + (size_t)j * (DIN * DST));

#pragma unroll
  for (int j = 0; j < 16; ++j) {
    const float4 h4 = hbuf[j & 3];
    if (j + 4 < 16)
      hbuf[j & 3] = *(const float4*)(hp + (size_t)(j + 4) * (DIN * DST));

    const float dtv = sDT[w][j][Q];
    const float xv  = sX[w][j][Q];
    const float dtx = dtv * xv;
    const float4 B4 = *(const float4*)&sB[w][j][q * 4];
    const float4 C4 = *(const float4*)&sC[w][j][q * 4];

    const float dA0 = __expf(A4.x * dtv);
    const float dA1 = __expf(A4.y * dtv);
    const float dA2 = __expf(A4.z * dtv);
    const float dA3 = __expf(A4.w * dtv);
    const float hn0 = fmaf(dA0, h4.x, dtx * B4.x);
    const float hn1 = fmaf(dA1, h4.y, dtx * B4.y);
    const float hn2 = fmaf(dA2, h4.z, dtx * B4.z);
    const float hn3 = fmaf(dA3, h4.w, dtx * B4.w);
    float p = hn0 * C4.x + hn1 * C4.y + hn2 * C4.z + hn3 * C4.w;

    p += __shfl_xor(p, 1);
    p += __shfl_xor(p, 2);
    if (q == 0) yp[(size_t)j * DIN] = fmaf(Dv, xv, p);
  }
}

extern "C" void kernel_launch(void* const* d_in, const int* in_sizes, int n_in,
                              void* d_out, int out_size, void* d_ws, size_t ws_size,
                              hipStream_t stream) {
  const float* x    = (const float*)d_in[0];
  const float* Wdtr = (const float*)d_in[1];
  const float* Wdt  = (const float*)d_in[2];
  const float* bdt  = (const float*)d_in[3];
  const float* WB   = (const float*)d_in[4];
  const float* WC   = (const float*)d_in[5];
  const float* A    = (const float*)d_in[6];
  const float* Dp   = (const float*)d_in[7];
  const float* h    = (const float*)d_in[8];
  float* y = (float*)d_out;
  char* ws = (char*)d_ws;

  k_prep3<<<dim3(960), 256, 0, stream>>>(x, Wdtr, WB, WC, Wdt, ws);
  k_g1f2<<<dim3(384), 1024, 0, stream>>>(ws);
  k_g2y<<<dim3(2560), 256, 0, stream>>>(bdt, A, Dp, x, h, y, ws);
}

// Round 16
// 50.201 us; speedup vs baseline: 1.9457x; 1.0302x over previous
//
#include <hip/hip_runtime.h>
#include <math.h>

#define BATCH 512
#define DIN   5120
#define DST   16
#define RK    160
#define NJ    192     // 160 dt_rank + 16 B + 16 C

typedef __attribute__((ext_vector_type(8))) __bf16 bf16x8;
typedef __attribute__((ext_vector_type(4))) float f32x4;
typedef __attribute__((ext_vector_type(8))) unsigned short ushort8;

// ws byte offsets (all 16B aligned)
#define OFF_XP    0u          // xP   [640 k8][512 b][8]  bf16
#define OFF_WP    5242880u    // WP   [640 k8][192 j][8]  bf16
#define OFF_WDTP  7208960u    // WdtP [20 k8][5120 d][8]  bf16
#define OFF_DTRP  8847360u    // dtrP [20 k8][512 b][8]   bf16
#define OFF_B     9011200u    // Bc   [512][16] f32
#define OFF_C     9043968u    // Cc   [512][16] f32

__device__ __forceinline__ unsigned short f2bf(float f) {
  unsigned int u = __float_as_uint(f);
  u = (u + 0x7FFFu + ((u >> 16) & 1u)) >> 16;   // RNE
  return (unsigned short)u;
}

// ---------------------------------------------------------------------------
// k_prep3: bf16 pack via LDS tile-transpose, 960 blocks (R15, unchanged).
// ---------------------------------------------------------------------------
__global__ __launch_bounds__(256) void k_prep3(
    const float* __restrict__ x, const float* __restrict__ Wdtr,
    const float* __restrict__ WB, const float* __restrict__ WC,
    const float* __restrict__ Wdt, char* __restrict__ ws)
{
  __shared__ unsigned short sT[64 * 168];
  const int t = threadIdx.x;
  const int bid = blockIdx.x;

  if (bid < 640) {            // ---- job A: xP ----
    const int bt = bid & 7, kt = bid >> 3;
    const int b0 = bt * 64, k0 = kt * 64;
#pragma unroll
    for (int i = 0; i < 4; ++i) {
      const int f = i * 256 + t;
      const int r = f >> 4, c = f & 15;
      const float4 v = *(const float4*)&x[(size_t)(b0 + r) * DIN + k0 + c * 4];
      unsigned short* p = &sT[r * 72 + c * 4];
      p[0] = f2bf(v.x); p[1] = f2bf(v.y); p[2] = f2bf(v.z); p[3] = f2bf(v.w);
    }
    __syncthreads();
    ushort8* xP = (ushort8*)(ws + OFF_XP);
#pragma unroll
    for (int i = 0; i < 2; ++i) {
      const int o = i * 256 + t;
      const int k8l = o >> 6, bl = o & 63;
      const unsigned short* p = &sT[bl * 72 + k8l * 8];
      ushort8 v;
#pragma unroll
      for (int e = 0; e < 8; ++e) v[e] = p[e];
      xP[(size_t)(kt * 8 + k8l) * 512 + b0 + bl] = v;
    }
  } else if (bid < 880) {     // ---- job B: WP ----
    const int bb = bid - 640;
    const int jt = bb % 3, kt = bb / 3;
    const int j0 = jt * 64, k0 = kt * 64;
#pragma unroll
    for (int i = 0; i < 4; ++i) {
      const int f = i * 256 + t;
      const int r = f >> 4, c = f & 15;
      const int j = j0 + r;
      const float* row;
      if (j < RK)            row = Wdtr + (size_t)j * DIN;
      else if (j < RK + DST) row = WB   + (size_t)(j - RK) * DIN;
      else                   row = WC   + (size_t)(j - RK - DST) * DIN;
      const float4 v = *(const float4*)&row[k0 + c * 4];
      unsigned short* p = &sT[r * 72 + c * 4];
      p[0] = f2bf(v.x); p[1] = f2bf(v.y); p[2] = f2bf(v.z); p[3] = f2bf(v.w);
    }
    __syncthreads();
    ushort8* WPo = (ushort8*)(ws + OFF_WP);
#pragma unroll
    for (int i = 0; i < 2; ++i) {
      const int o = i * 256 + t;
      const int k8l = o >> 6, jl = o & 63;
      const unsigned short* p = &sT[jl * 72 + k8l * 8];
      ushort8 v;
#pragma unroll
      for (int e = 0; e < 8; ++e) v[e] = p[e];
      WPo[(size_t)(kt * 8 + k8l) * 192 + j0 + jl] = v;
    }
  } else {                    // ---- job C: WdtP ----
    const int d0 = (bid - 880) * 64;
#pragma unroll
    for (int i = 0; i < 10; ++i) {
      const int f = i * 256 + t;
      const int r = f / 40, c = f - r * 40;
      const float4 v = *(const float4*)&Wdt[(size_t)(d0 + r) * RK + c * 4];
      unsigned short* p = &sT[r * 168 + c * 4];
      p[0] = f2bf(v.x); p[1] = f2bf(v.y); p[2] = f2bf(v.z); p[3] = f2bf(v.w);
    }
    __syncthreads();
    ushort8* WdtPo = (ushort8*)(ws + OFF_WDTP);
#pragma unroll
    for (int i = 0; i < 5; ++i) {
      const int o = i * 256 + t;
      const int k8l = o >> 6, dl = o & 63;
      const unsigned short* p = &sT[dl * 168 + k8l * 8];
      ushort8 v;
#pragma unroll
      for (int e = 0; e < 8; ++e) v[e] = p[e];
      WdtPo[(size_t)k8l * 5120 + d0 + dl] = v;
    }
  }
}

// ---------------------------------------------------------------------------
// k_g1f2: GEMM1 with in-block split-K (R15, unchanged). 384 x 1024.
// ---------------------------------------------------------------------------
__global__ __launch_bounds__(1024) void k_g1f2(char* __restrict__ ws)
{
  __shared__ float4 red[16][64];

  const int t = threadIdx.x;
  const int w = t >> 6, l = t & 63;
  const int jt = blockIdx.x >> 5, bt = blockIdx.x & 31;
  const int j0 = jt * 16, b0 = bt * 16;

  const bf16x8* WPv = (const bf16x8*)(ws + OFF_WP);
  const bf16x8* xPv = (const bf16x8*)(ws + OFF_XP);

  const int lg = l >> 4, lr = l & 15;
  f32x4 acc = {0.f, 0.f, 0.f, 0.f};

#pragma unroll
  for (int s = 0; s < 10; ++s) {
    const int k8 = w * 40 + s * 4 + lg;
    const bf16x8 av = WPv[(size_t)k8 * 192 + j0 + lr];
    const bf16x8 bv = xPv[(size_t)k8 * 512 + b0 + lr];
    acc = __builtin_amdgcn_mfma_f32_16x16x32_bf16(av, bv, acc, 0, 0, 0);
  }

  red[w][l] = (float4){acc[0], acc[1], acc[2], acc[3]};
  __syncthreads();

  if (t < 256) {
    const int ll = t >> 2, r = t & 3;
    const float* rp = (const float*)red;
    float s = 0.f;
#pragma unroll
    for (int ww = 0; ww < 16; ++ww)
      s += rp[(ww * 64 + ll) * 4 + r];

    const int j = j0 + (ll >> 4) * 4 + r;
    const int b = b0 + (ll & 15);
    if (jt < 10) {
      unsigned short* dtrP = (unsigned short*)(ws + OFF_DTRP);
      dtrP[((size_t)(j >> 3) * 512 + b) * 8 + (j & 7)] = f2bf(s);
    } else if (jt == 10) {
      ((float*)(ws + OFF_B))[(size_t)b * DST + (j - 160)] = s;
    } else {
      ((float*)(ws + OFF_C))[(size_t)b * DST + (j - 176)] = s;
    }
  }
}

// ---------------------------------------------------------------------------
// k_g2y2: fused dt-GEMM + softplus + h-stream, one wave per 16b x 32d task.
// 5120 tasks = 1280 blocks x 4 waves = exactly 20 waves/CU: SINGLE batch.
// dtrP A-fragments reused across both d-halves; 2KB h in flight per j.
// ---------------------------------------------------------------------------
__global__ __launch_bounds__(256) void k_g2y2(
    const float* __restrict__ bdt, const float* __restrict__ A,
    const float* __restrict__ Dp,  const float* __restrict__ x,
    const float* __restrict__ h,   float* __restrict__ y,
    char* __restrict__ ws)
{
  __shared__ float sDT[4][16][33];
  __shared__ float sB[4][16][16];
  __shared__ float sC[4][16][16];
  __shared__ float sX[4][16][32];

  const int w = threadIdx.x >> 6;
  const int l = threadIdx.x & 63;
  const int wid = blockIdx.x * 4 + w;           // 0..5119
  const int dtile = wid % 160, btile = wid / 160;
  const int d0 = dtile * 32, b0 = btile * 16;

  const bf16x8* dtrPv = (const bf16x8*)(ws + OFF_DTRP);
  const bf16x8* WdtPv = (const bf16x8*)(ws + OFF_WDTP);
  const float*  Bc    = (const float*)(ws + OFF_B);
  const float*  Cc    = (const float*)(ws + OFF_C);

  // stage Bc/Cc (16x16 each) and x tile (16b x 32d)
  *(float4*)&((float*)sB[w])[l * 4] = *(const float4*)&Bc[b0 * DST + l * 4];
  *(float4*)&((float*)sC[w])[l * 4] = *(const float4*)&Cc[b0 * DST + l * 4];
#pragma unroll
  for (int i = 0; i < 2; ++i) {
    const int o = i * 64 + l;                   // 0..127
    const int xr = o >> 3, xc = (o & 7) * 4;
    *(float4*)&sX[w][xr][xc] = *(const float4*)&x[(size_t)(b0 + xr) * DIN + d0 + xc];
  }

  // dt tiles via MFMA (both d-halves share the dtrP A-fragment)
  const int lg = l >> 4, lr = l & 15;
  f32x4 acc0 = {0.f, 0.f, 0.f, 0.f}, acc1 = acc0;
#pragma unroll
  for (int s = 0; s < 5; ++s) {
    const int k8 = s * 4 + lg;
    const bf16x8 av  = dtrPv[(size_t)k8 * 512 + b0 + lr];
    const bf16x8 bv0 = WdtPv[(size_t)k8 * 5120 + d0 + lr];
    const bf16x8 bv1 = WdtPv[(size_t)k8 * 5120 + d0 + 16 + lr];
    acc0 = __builtin_amdgcn_mfma_f32_16x16x32_bf16(av, bv0, acc0, 0, 0, 0);
    acc1 = __builtin_amdgcn_mfma_f32_16x16x32_bf16(av, bv1, acc1, 0, 0, 0);
  }
  const float bias0 = bdt[d0 + lr];
  const float bias1 = bdt[d0 + 16 + lr];
#pragma unroll
  for (int r = 0; r < 4; ++r) {
    const float p0 = acc0[r] + bias0;
    const float p1 = acc1[r] + bias1;
    sDT[w][lg * 4 + r][lr]      = (p0 > 20.f) ? p0 : log1pf(__expf(p0));
    sDT[w][lg * 4 + r][16 + lr] = (p1 > 20.f) ? p1 : log1pf(__expf(p1));
  }
  __syncthreads();

  // h-stream: quad q owns states q*4..q*4+3; Q = d offset; two d's per lane.
  const int q = l & 3;
  const int Q = l >> 2;
  const int dA_ = d0 + Q, dB_ = d0 + 16 + Q;

  const float4 Aa = *(const float4*)(A + (size_t)dA_ * DST + q * 4);
  const float4 Ab = *(const float4*)(A + (size_t)dB_ * DST + q * 4);
  const float  DvA = Dp[dA_], DvB = Dp[dB_];

  const float* hpA = h + ((size_t)b0 * DIN + dA_) * DST + q * 4;
  const float* hpB = h + ((size_t)b0 * DIN + dB_) * DST + q * 4;
  float* ypA = y + (size_t)b0 * DIN + dA_;
  float* ypB = y + (size_t)b0 * DIN + dB_;
  const size_t jstep = (size_t)DIN * DST;

  // depth-2 rotating prefetch (static indices)
  float4 hA0 = *(const float4*)(hpA);
  float4 hB0 = *(const float4*)(hpB);
  float4 hA1 = *(const float4*)(hpA + jstep);
  float4 hB1 = *(const float4*)(hpB + jstep);

#pragma unroll
  for (int j = 0; j < 16; ++j) {
    const float4 h4a = (j & 1) ? hA1 : hA0;
    const float4 h4b = (j & 1) ? hB1 : hB0;
    if (j + 2 < 16) {
      if (j & 1) { hA1 = *(const float4*)(hpA + (size_t)(j + 2) * jstep);
                   hB1 = *(const float4*)(hpB + (size_t)(j + 2) * jstep); }
      else       { hA0 = *(const float4*)(hpA + (size_t)(j + 2) * jstep);
                   hB0 = *(const float4*)(hpB + (size_t)(j + 2) * jstep); }
    }

    const float4 B4 = *(const float4*)&sB[w][j][q * 4];
    const float4 C4 = *(const float4*)&sC[w][j][q * 4];

    const float dtvA = sDT[w][j][Q];
    const float dtvB = sDT[w][j][16 + Q];
    const float xvA  = sX[w][j][Q];
    const float xvB  = sX[w][j][16 + Q];
    const float dtxA = dtvA * xvA;
    const float dtxB = dtvB * xvB;

    float pA, pB;
    {
      const float e0 = __expf(Aa.x * dtvA), e1 = __expf(Aa.y * dtvA);
      const float e2 = __expf(Aa.z * dtvA), e3 = __expf(Aa.w * dtvA);
      const float n0 = fmaf(e0, h4a.x, dtxA * B4.x);
      const float n1 = fmaf(e1, h4a.y, dtxA * B4.y);
      const float n2 = fmaf(e2, h4a.z, dtxA * B4.z);
      const float n3 = fmaf(e3, h4a.w, dtxA * B4.w);
      pA = n0 * C4.x + n1 * C4.y + n2 * C4.z + n3 * C4.w;
    }
    {
      const float e0 = __expf(Ab.x * dtvB), e1 = __expf(Ab.y * dtvB);
      const float e2 = __expf(Ab.z * dtvB), e3 = __expf(Ab.w * dtvB);
      const float n0 = fmaf(e0, h4b.x, dtxB * B4.x);
      const float n1 = fmaf(e1, h4b.y, dtxB * B4.y);
      const float n2 = fmaf(e2, h4b.z, dtxB * B4.z);
      const float n3 = fmaf(e3, h4b.w, dtxB * B4.w);
      pB = n0 * C4.x + n1 * C4.y + n2 * C4.z + n3 * C4.w;
    }

    pA += __shfl_xor(pA, 1);
    pA += __shfl_xor(pA, 2);
    pB += __shfl_xor(pB, 1);
    pB += __shfl_xor(pB, 2);
    if (q == 0) {
      ypA[(size_t)j * DIN] = fmaf(DvA, xvA, pA);
      ypB[(size_t)j * DIN] = fmaf(DvB, xvB, pB);
    }
  }
}

extern "C" void kernel_launch(void* const* d_in, const int* in_sizes, int n_in,
                              void* d_out, int out_size, void* d_ws, size_t ws_size,
                              hipStream_t stream) {
  const float* x    = (const float*)d_in[0];
  const float* Wdtr = (const float*)d_in[1];
  const float* Wdt  = (const float*)d_in[2];
  const float* bdt  = (const float*)d_in[3];
  const float* WB   = (const float*)d_in[4];
  const float* WC   = (const float*)d_in[5];
  const float* A    = (const float*)d_in[6];
  const float* Dp   = (const float*)d_in[7];
  const float* h    = (const float*)d_in[8];
  float* y = (float*)d_out;
  char* ws = (char*)d_ws;

  k_prep3<<<dim3(960), 256, 0, stream>>>(x, Wdtr, WB, WC, Wdt, ws);
  k_g1f2<<<dim3(384), 1024, 0, stream>>>(ws);
  k_g2y2<<<dim3(1280), 256, 0, stream>>>(bdt, A, Dp, x, h, y, ws);
}